// Round 7
// baseline (36928.043 us; speedup 1.0000x reference)
//
#include <hip/hip_runtime.h>
#include <hip/hip_bf16.h>

// IEBins forward. Round 18: r17 + TAIL-PACKED k_zrx (unequal-wave schedule).
// r17 post-mortem: out-ch pairing real but small (-4%). In-round busy
// ~88% (VALUBusy 52% / util 59%) — issue-bound while running; the waste is
// the dispatch tail: 2432 equal blocks on 2048 slots -> makespan 2T with
// 81% idle in round 2. r15 showed finer UNIFORM waves explode FETCH; fix
// is UNEQUAL waves: exactly 2048 blocks (8192 waves, all resident at t=0)
// cover the 19456 (tile,outch-pair) units. Per XCD: 2432 pairs / 1024
// waves = 2.375: 5120 waves do one NACC=4 sweep (2 pairs, T), 3072 do
// NACC=4 + NACC=2 (3 pairs, 1.62T). Makespan 2T -> 1.62T. Consecutive
// waves take consecutive tile-major pair ranges (same-XCD locality kept).
// Arithmetic FROZEN: every output chain runs the identical r9-order sweep
// (tap-outer, seg H,d4,ctx, chunk-32 f32 partials -> f64 masters, channels
// ascending); a pair merely executes on a different wave. absmax 1.0.
// e4/others unchanged this round (contained blast radius).

#define HD  128
#define CDC 192
#define BN  16
#define OCH 256
#define GC  576
#define NB  2
#define HH  120
#define WW  160
#define HW  (HH*WW)
#define BHW (NB*HW)
#define PXT (BHW/128)          // 300 pixel tiles of 128 px
#define GXP (((PXT+7)/8)*8)    // 304 padded
#define TPX (GXP/8)            // 38 tiles per XCD slab
#define ZPAIRS (TPX*64)        // 2432 outch-pairs per XCD slab (zrx)
// padded plane geometry: 3 halo rows top/bottom, 4 cols left/right
#define PWW 168
#define PHH 126
#define PHW (PWW*PHH)          // 21168
#define POFF(y,x) (((y)+3)*PWW + (x) + 4)

__device__ __forceinline__ float2 ldf2(const float* p){ return *(const float2*)p; }
__device__ __forceinline__ void stf2(float* p, float a, float b){
  *(float2*)p = make_float2(a,b);
}

// packed pair type (4B-aligned loads ok on gfx9+).
typedef float f2 __attribute__((ext_vector_type(2), aligned(4)));
// uniform base + unsigned 32-bit offset -> global_load saddr form.
__device__ __forceinline__ f2 ldpo(const float* __restrict__ base, const unsigned off){
  return *(const f2*)(base + off);
}
// uniform weight-pair load (wave-uniform address -> s_load_dwordx2).
__device__ __forceinline__ f2 ldw2(const float* __restrict__ p){ return *(const f2*)p; }

// packed FMA on two out-channels: a.{lo,hi} += v * w.{lo,hi}
__device__ __forceinline__ void pkfma2(f2& a, const f2 v, const f2 w){
  a = __builtin_elementwise_fma(v, w, a);
}

// ---------------------------------------------------------------- zero ----
__global__ __launch_bounds__(256) void k_zero32(float* __restrict__ p, const size_t n){
  const size_t i = (size_t)blockIdx.x*256 + threadIdx.x;
  for (size_t k=i; k<n; k += (size_t)gridDim.x*256) p[k] = 0.f;
}
__global__ __launch_bounds__(256) void k_zero64(double* __restrict__ p, const size_t n){
  const size_t i = (size_t)blockIdx.x*256 + threadIdx.x;
  for (size_t k=i; k<n; k += (size_t)gridDim.x*256) p[k] = 0.0;
}

// ------------------------------------------------------------- pad ctx ----
__global__ __launch_bounds__(256) void k_pad(const float* __restrict__ src,
        float* __restrict__ dst, const int nplanes){
  const int i = blockIdx.x*256 + threadIdx.x;
  if (i >= nplanes*HW) return;
  const int bc = i / HW, r = i - bc*HW;
  const int y = r / WW, x = r - y*WW;
  dst[(size_t)bc*PHW + POFF(y,x)] = src[i];
}

// ---------------------------------------------------------------- init ----
__global__ __launch_bounds__(256) void k_init(const float* __restrict__ gh,
        float* __restrict__ h, double* __restrict__ edges, double* __restrict__ cdp){
  const int i = blockIdx.x*256 + threadIdx.x;
  const int nh = NB*HD*HW;
  if (i < nh){
    const int bc = i / HW, r = i - bc*HW;
    const int y = r / WW, x = r - y*WW;
    h[(size_t)bc*PHW + POFF(y,x)] = gh[i];
  }
  if (i < BHW){
    const int b = i / HW, r = i - b*HW;
    const int y = r / WW, x = r - y*WW;
    const int pr = POFF(y,x);
    double e = 0.0;
    #pragma unroll
    for (int k=0;k<BN;++k){
      edges[(b*(BN+1)+k)*HW + r] = e;
      cdp[((size_t)b*BN+k)*PHW + pr] = e + 2.5;
      e += 5.0;
    }
    edges[(b*(BN+1)+BN)*HW + r] = e;   // 80
  }
}

// ------------------------------------------------- weight transpose ------
// w[o][c][tap] f32  ->  wt[(c*TAPS+t)*Cout + o]
__global__ __launch_bounds__(256) void k_wxpose(const float* __restrict__ w,
        float* __restrict__ wt, const int Cout, const int CIN, const int TAPS,
        const int n){
  const int i = blockIdx.x*256 + threadIdx.x;
  if (i >= n) return;
  const int ct = CIN*TAPS;
  const int o = i / ct;
  const int rem = i - o*ct;
  const int c = rem / TAPS;
  const int t = rem - c*TAPS;
  wt[((size_t)c*TAPS + t)*Cout + o] = w[i];
}

// ------------------------------------------- XCD-aware block decode ------
template<int GY>
__device__ __forceinline__ bool blk_decode(int& xs, int& yg){
  const int id  = blockIdx.x;
  const int xcd = id & 7;
  const int s   = id >> 3;
  yg = s & (GY-1);
  const int k = s / GY;
  xs = xcd*TPX + k;
  return xs < PXT;
}

// pair-pixel decode: lane -> 2 adjacent px (x even)
__device__ __forceinline__ void pair_decode(const int xs, int& b, int& r0, int& po){
  const int lane = threadIdx.x & 63;
  const int pb = xs*128;
  b = pb / HW;
  r0 = pb - b*HW + 2*lane;
  const int y = r0 / WW, x = r0 - y*WW;
  po = POFF(y,x);
}

// ------------------------------------------------ e1: 7x7, 16ch, f64 in --
// tap outer, single 16-ch f32 chunk (r9 order); out-ch-pair packed FMA.
__global__ __launch_bounds__(256) void k_e1(const double* __restrict__ cdp,
        const float* __restrict__ wt, const float* __restrict__ bias,
        float* __restrict__ out){
  const int NACC = 8, NP = NACC/2;
  int xs, yg;
  if (!blk_decode<4>(xs, yg)) return;
  const int wvu = __builtin_amdgcn_readfirstlane((int)(threadIdx.x >> 6));
  const int ow0 = (yg*4 + wvu)*NACC;
  int b, r0, po;
  pair_decode(xs, b, r0, po);
  double acc[2][NACC];
  #pragma unroll
  for (int j=0;j<NACC;++j){
    const double bj = (double)bias[ow0+j];
    acc[0][j]=bj; acc[1][j]=bj;
  }
  const double* inb = cdp + (size_t)b*16*PHW;
  #pragma unroll 1
  for (int t=0;t<49;++t){
    const unsigned pot = (unsigned)(po + (t/7 - 3)*PWW + (t%7 - 3));
    f2 ca[2][NP];
    #pragma unroll
    for (int p=0;p<NP;++p){ ca[0][p]=f2{0.f,0.f}; ca[1][p]=f2{0.f,0.f}; }
    const float* wr = wt + (size_t)t*HD + ow0;
    #pragma unroll 4
    for (int c=0;c<16;++c){
      const double* pp = inb + (size_t)c*PHW;      // uniform base
      const float v0 = (float)pp[pot];
      const float v1 = (float)pp[pot+1u];
      const f2 v00 = {v0, v0};
      const f2 v11 = {v1, v1};
      #pragma unroll
      for (int p=0;p<NP;++p){
        const f2 wp_ = ldw2(wr + 2*p);
        pkfma2(ca[0][p], v00, wp_);
        pkfma2(ca[1][p], v11, wp_);
      }
      wr += (size_t)49*HD;
    }
    #pragma unroll
    for (int p=0;p<NP;++p){
      acc[0][2*p]  +=(double)ca[0][p].x; acc[0][2*p+1]+=(double)ca[0][p].y;
      acc[1][2*p]  +=(double)ca[1][p].x; acc[1][2*p+1]+=(double)ca[1][p].y;
    }
  }
  #pragma unroll
  for (int j=0;j<NACC;++j){
    double v0 = acc[0][j]; v0 = v0>0.0?v0:0.0;
    double v1 = acc[1][j]; v1 = v1>0.0?v1:0.0;
    stf2(out + ((size_t)b*HD + ow0 + j)*PHW + po, (float)v0, (float)v1);
  }
}

// ------------------------------------------------ 3x3 conv, 128ch, f32 ---
// r9 fconv order: tap OUTER, chunk-32 inner; out-ch-pair packed FMA.
template<int NACC,int GY,int ACT>
__global__ __launch_bounds__(256) void k_fc3(const float* __restrict__ in,
        const float* __restrict__ wt, const float* __restrict__ bias,
        float* __restrict__ out, const int Cout){
  const int NP = NACC/2;
  int xs, yg;
  if (!blk_decode<GY>(xs, yg)) return;
  const int wvu = __builtin_amdgcn_readfirstlane((int)(threadIdx.x >> 6));
  const int ow0 = (yg*4 + wvu)*NACC;
  int b, r0, po;
  pair_decode(xs, b, r0, po);
  double acc[2][NACC];
  #pragma unroll
  for (int j=0;j<NACC;++j){
    const double bj = (double)bias[ow0+j];
    acc[0][j]=bj; acc[1][j]=bj;
  }
  const float* inb = in + (size_t)b*128*PHW;
  #pragma unroll 1
  for (int t=0;t<9;++t){
    const unsigned pot = (unsigned)(po + (t/3 - 1)*PWW + (t%3 - 1));
    #pragma unroll 1
    for (int c0=0;c0<128;c0+=32){
      f2 ca[2][NP];
      #pragma unroll
      for (int p=0;p<NP;++p){ ca[0][p]=f2{0.f,0.f}; ca[1][p]=f2{0.f,0.f}; }
      const float* wr = wt + ((size_t)c0*9 + t)*Cout + ow0;
      #pragma unroll 8
      for (int c=0;c<32;++c){
        const f2 v = ldpo(inb + (size_t)(c0+c)*PHW, pot);
        const f2 v00 = {v.x, v.x};
        const f2 v11 = {v.y, v.y};
        #pragma unroll
        for (int p=0;p<NP;++p){
          const f2 wp_ = ldw2(wr + 2*p);
          pkfma2(ca[0][p], v00, wp_);
          pkfma2(ca[1][p], v11, wp_);
        }
        wr += (size_t)9*Cout;
      }
      #pragma unroll
      for (int p=0;p<NP;++p){
        acc[0][2*p]  +=(double)ca[0][p].x; acc[0][2*p+1]+=(double)ca[0][p].y;
        acc[1][2*p]  +=(double)ca[1][p].x; acc[1][2*p+1]+=(double)ca[1][p].y;
      }
    }
  }
  #pragma unroll
  for (int j=0;j<NACC;++j){
    double v0 = acc[0][j], v1 = acc[1][j];
    if (ACT==1){ v0 = v0>0.0?v0:0.0; v1 = v1>0.0?v1:0.0; }
    stf2(out + ((size_t)b*Cout + ow0 + j)*PHW + po, (float)v0, (float)v1);
  }
}

// ------------------------------------------- GRU segments (r9 order) -----
// Two-gate (z,r); chunk-32 f32; out-ch-pair packed FMA; unroll 4.
template<int C,int NACC>
__device__ __forceinline__ void seg2(const float* __restrict__ plane, const unsigned pot,
    const float* __restrict__ wz0, const float* __restrict__ wr0,
    double az[2][NACC], double ar[2][NACC]){
  const int NP = NACC/2;
  #pragma unroll 1
  for (int c0=0;c0<C;c0+=32){
    f2 cz[2][NP], cr[2][NP];
    #pragma unroll
    for (int p=0;p<NP;++p){
      cz[0][p]=f2{0.f,0.f}; cz[1][p]=f2{0.f,0.f};
      cr[0][p]=f2{0.f,0.f}; cr[1][p]=f2{0.f,0.f};
    }
    const float* wz = wz0 + (size_t)c0*5*HD;
    const float* wr = wr0 + (size_t)c0*5*HD;
    #pragma unroll 4
    for (int c=0;c<32;++c){
      const f2 v = ldpo(plane + (size_t)(c0+c)*PHW, pot);
      const f2 v00 = {v.x, v.x};
      const f2 v11 = {v.y, v.y};
      #pragma unroll
      for (int p=0;p<NP;++p){
        const f2 wzp = ldw2(wz + 2*p);
        const f2 wrp = ldw2(wr + 2*p);
        pkfma2(cz[0][p], v00, wzp); pkfma2(cz[1][p], v11, wzp);
        pkfma2(cr[0][p], v00, wrp); pkfma2(cr[1][p], v11, wrp);
      }
      wz += 5*HD; wr += 5*HD;
    }
    #pragma unroll
    for (int p=0;p<NP;++p){
      az[0][2*p]+=(double)cz[0][p].x; az[0][2*p+1]+=(double)cz[0][p].y;
      az[1][2*p]+=(double)cz[1][p].x; az[1][2*p+1]+=(double)cz[1][p].y;
      ar[0][2*p]+=(double)cr[0][p].x; ar[0][2*p+1]+=(double)cr[0][p].y;
      ar[1][2*p]+=(double)cr[1][p].x; ar[1][2*p+1]+=(double)cr[1][p].y;
    }
  }
}
// Three-gate (z,r,qx).
template<int C,int NACC>
__device__ __forceinline__ void seg3(const float* __restrict__ plane, const unsigned pot,
    const float* __restrict__ wz0, const float* __restrict__ wr0,
    const float* __restrict__ wq0,
    double az[2][NACC], double ar[2][NACC], double aq[2][NACC]){
  const int NP = NACC/2;
  #pragma unroll 1
  for (int c0=0;c0<C;c0+=32){
    f2 cz[2][NP], cr[2][NP], cq[2][NP];
    #pragma unroll
    for (int p=0;p<NP;++p){
      cz[0][p]=f2{0.f,0.f}; cz[1][p]=f2{0.f,0.f};
      cr[0][p]=f2{0.f,0.f}; cr[1][p]=f2{0.f,0.f};
      cq[0][p]=f2{0.f,0.f}; cq[1][p]=f2{0.f,0.f};
    }
    const float* wz = wz0 + (size_t)c0*5*HD;
    const float* wr = wr0 + (size_t)c0*5*HD;
    const float* wq = wq0 + (size_t)c0*5*HD;
    #pragma unroll 4
    for (int c=0;c<32;++c){
      const f2 v = ldpo(plane + (size_t)(c0+c)*PHW, pot);
      const f2 v00 = {v.x, v.x};
      const f2 v11 = {v.y, v.y};
      #pragma unroll
      for (int p=0;p<NP;++p){
        const f2 wzp = ldw2(wz + 2*p);
        const f2 wrp = ldw2(wr + 2*p);
        const f2 wqp = ldw2(wq + 2*p);
        pkfma2(cz[0][p], v00, wzp); pkfma2(cz[1][p], v11, wzp);
        pkfma2(cr[0][p], v00, wrp); pkfma2(cr[1][p], v11, wrp);
        pkfma2(cq[0][p], v00, wqp); pkfma2(cq[1][p], v11, wqp);
      }
      wz += 5*HD; wr += 5*HD; wq += 5*HD;
    }
    #pragma unroll
    for (int p=0;p<NP;++p){
      az[0][2*p]+=(double)cz[0][p].x; az[0][2*p+1]+=(double)cz[0][p].y;
      az[1][2*p]+=(double)cz[1][p].x; az[1][2*p+1]+=(double)cz[1][p].y;
      ar[0][2*p]+=(double)cr[0][p].x; ar[0][2*p+1]+=(double)cr[0][p].y;
      ar[1][2*p]+=(double)cr[1][p].x; ar[1][2*p+1]+=(double)cr[1][p].y;
      aq[0][2*p]+=(double)cq[0][p].x; aq[0][2*p+1]+=(double)cq[0][p].y;
      aq[1][2*p]+=(double)cq[1][p].x; aq[1][2*p+1]+=(double)cq[1][p].y;
    }
  }
}
// One-gate (qh); unroll 8.
template<int C,int NACC>
__device__ __forceinline__ void seg1(const float* __restrict__ plane, const unsigned pot,
    const float* __restrict__ wq0, double aq[2][NACC]){
  const int NP = NACC/2;
  #pragma unroll 1
  for (int c0=0;c0<C;c0+=32){
    f2 cq[2][NP];
    #pragma unroll
    for (int p=0;p<NP;++p){ cq[0][p]=f2{0.f,0.f}; cq[1][p]=f2{0.f,0.f}; }
    const float* wq = wq0 + (size_t)c0*5*HD;
    #pragma unroll 8
    for (int c=0;c<32;++c){
      const f2 v = ldpo(plane + (size_t)(c0+c)*PHW, pot);
      const f2 v00 = {v.x, v.x};
      const f2 v11 = {v.y, v.y};
      #pragma unroll
      for (int p=0;p<NP;++p){
        const f2 wqp = ldw2(wq + 2*p);
        pkfma2(cq[0][p], v00, wqp);
        pkfma2(cq[1][p], v11, wqp);
      }
      wq += 5*HD;
    }
    #pragma unroll
    for (int p=0;p<NP;++p){
      aq[0][2*p]+=(double)cq[0][p].x; aq[0][2*p+1]+=(double)cq[0][p].y;
      aq[1][2*p]+=(double)cq[1][p].x; aq[1][2*p+1]+=(double)cq[1][p].y;
    }
  }
}

// ------------------- zrx sweep: one full GRU-gate accumulation -----------
// Identical arithmetic to r17's k_zrx body for out-channels [ow0, ow0+NACC).
template<int VERT,int NACC>
__device__ __forceinline__ void zrx_sweep(const int xs, const int ow0,
    const float* __restrict__ h, const float* __restrict__ d4,
    const float* __restrict__ ctxp,
    const float* __restrict__ wtz, const float* __restrict__ wtr,
    const float* __restrict__ wtq,
    const float* __restrict__ bz, const float* __restrict__ br,
    const float* __restrict__ bq,
    float* __restrict__ zg, float* __restrict__ rgh, float* __restrict__ qx){
  int b, r0, po;
  pair_decode(xs, b, r0, po);
  double az[2][NACC], ar[2][NACC], aq[2][NACC];
  #pragma unroll
  for (int j=0;j<NACC;++j){
    const double bzj=(double)bz[ow0+j], brj=(double)br[ow0+j], bqj=(double)bq[ow0+j];
    az[0][j]=bzj; az[1][j]=bzj; ar[0][j]=brj; ar[1][j]=brj; aq[0][j]=bqj; aq[1][j]=bqj;
  }
  const float* hb = h   + (size_t)b*HD *PHW;
  const float* db = d4  + (size_t)b*OCH*PHW;
  const float* cb = ctxp+ (size_t)b*CDC*PHW;
  #pragma unroll 1
  for (int t=0;t<5;++t){
    const unsigned pot = (unsigned)(po + (VERT ? (t-2)*PWW : (t-2)));
    seg2<HD ,NACC>(hb, pot, wtz + (size_t)t*HD + ow0,
                            wtr + (size_t)t*HD + ow0, az, ar);
    seg3<OCH,NACC>(db, pot, wtz + ((size_t)HD*5 + t)*HD + ow0,
                            wtr + ((size_t)HD*5 + t)*HD + ow0,
                            wtq + ((size_t)HD*5 + t)*HD + ow0, az, ar, aq);
    seg3<CDC,NACC>(cb, pot, wtz + ((size_t)(HD+OCH)*5 + t)*HD + ow0,
                            wtr + ((size_t)(HD+OCH)*5 + t)*HD + ow0,
                            wtq + ((size_t)(HD+OCH)*5 + t)*HD + ow0, az, ar, aq);
  }
  #pragma unroll
  for (int j=0;j<NACC;++j){
    const size_t pp = ((size_t)b*HD + ow0 + j)*PHW + po;
    const float2 hv = ldf2(h + pp);
    const double z0 = 1.0/(1.0+exp(-az[0][j])), z1 = 1.0/(1.0+exp(-az[1][j]));
    const double g0 = (1.0/(1.0+exp(-ar[0][j]))) * (double)hv.x;
    const double g1 = (1.0/(1.0+exp(-ar[1][j]))) * (double)hv.y;
    stf2(zg  + pp, (float)z0, (float)z1);
    stf2(rgh + pp, (float)g0, (float)g1);
    stf2(qx + ((size_t)b*HD + ow0 + j)*HW + r0, (float)aq[0][j], (float)aq[1][j]);
  }
}

// Fused z,r,qx: tail-packed scheduler. 2048 blocks, 8192 waves, each wave
// owns 2-3 consecutive (tile, outch-pair) units of its XCD slab.
template<int VERT>
__global__ __launch_bounds__(256) void k_zrx(
    const float* __restrict__ h, const float* __restrict__ d4,
    const float* __restrict__ ctxp,
    const float* __restrict__ wtz, const float* __restrict__ wtr,
    const float* __restrict__ wtq,
    const float* __restrict__ bz, const float* __restrict__ br,
    const float* __restrict__ bq,
    float* __restrict__ zg, float* __restrict__ rgh, float* __restrict__ qx){
  const int wvu = __builtin_amdgcn_readfirstlane((int)(threadIdx.x >> 6));
  const int xcd   = blockIdx.x & 7;
  const int bslot = blockIdx.x >> 3;            // 0..255
  const int w = bslot*4 + wvu;                  // 0..1023
  int p         = (w*ZPAIRS) >> 10;             // floor(w*2432/1024)
  const int pend = ((w+1)*ZPAIRS) >> 10;        // 2-3 pairs per wave
  #pragma unroll 1
  while (p < pend){
    const int tk = p >> 6;
    const int xs = xcd*TPX + tk;
    if (xs >= PXT) break;                       // padded tiles are tail of slab
    const int pr = p & 63;
    const bool fuse = (p+1 < pend) && (((p+1) >> 6) == tk);
    if (fuse){
      zrx_sweep<VERT,4>(xs, pr*2, h, d4, ctxp, wtz, wtr, wtq,
                        bz, br, bq, zg, rgh, qx);
      p += 2;
    } else {
      zrx_sweep<VERT,2>(xs, pr*2, h, d4, ctxp, wtz, wtr, wtq,
                        bz, br, bq, zg, rgh, qx);
      p += 1;
    }
  }
}

// q over rgh (128 ch) + hidden update. NACC=8, GY=4. Tap OUTER.
template<int VERT>
__global__ __launch_bounds__(256) void k_qh(
    const float* __restrict__ rgh, const float* __restrict__ wtq,
    const float* __restrict__ qx, const float* __restrict__ zg,
    float* __restrict__ h){
  const int NACC = 8;
  int xs, yg;
  if (!blk_decode<4>(xs, yg)) return;
  const int wvu = __builtin_amdgcn_readfirstlane((int)(threadIdx.x >> 6));
  const int ow0 = (yg*4 + wvu)*NACC;
  int b, r0, po;
  pair_decode(xs, b, r0, po);
  double aq[2][NACC];
  #pragma unroll
  for (int j=0;j<NACC;++j){
    const float2 q0 = ldf2(qx + ((size_t)b*HD + ow0 + j)*HW + r0);
    aq[0][j] = (double)q0.x; aq[1][j] = (double)q0.y;
  }
  const float* gb = rgh + (size_t)b*HD*PHW;
  #pragma unroll 1
  for (int t=0;t<5;++t){
    const unsigned pot = (unsigned)(po + (VERT ? (t-2)*PWW : (t-2)));
    seg1<HD,NACC>(gb, pot, wtq + (size_t)t*HD + ow0, aq);
  }
  #pragma unroll
  for (int j=0;j<NACC;++j){
    const size_t pp = ((size_t)b*HD + ow0 + j)*PHW + po;
    const float2 zv = ldf2(zg + pp);
    const float2 hv = ldf2(h  + pp);
    const double z0=(double)zv.x, z1=(double)zv.y;
    const double n0 = (1.0-z0)*(double)hv.x + z0*tanh(aq[0][j]);
    const double n1 = (1.0-z1)*(double)hv.y + z1*tanh(aq[1][j]);
    stf2(h + pp, (float)n0, (float)n1);
  }
}

// ------------------- softmax + depth_r + unc + label + cs + bin update ----
__global__ __launch_bounds__(256) void k_stats(const float* __restrict__ lg,
    double* __restrict__ edges, double* __restrict__ cdp, float* __restrict__ out,
    const int it){
  const int px = blockIdx.x*256 + threadIdx.x;
  const int b = px / HW, r = px - b*HW;
  const int y = r / WW, x = r - y*WW;
  const int pr = POFF(y,x);
  double l[BN], p[BN], c[BN];
  double m = -1e300;
  #pragma unroll
  for (int k=0;k<BN;++k){ l[k] = (double)lg[((size_t)b*BN+k)*PHW + pr]; m = l[k]>m?l[k]:m; }
  double s = 0.0;
  #pragma unroll
  for (int k=0;k<BN;++k){ p[k] = exp(l[k]-m); s += p[k]; }
  double dr = 0.0;
  #pragma unroll
  for (int k=0;k<BN;++k){ c[k] = cdp[((size_t)b*BN+k)*PHW + pr]; p[k] = p[k]/s; dr += p[k]*c[k]; }
  double var = 0.0;
  #pragma unroll
  for (int k=0;k<BN;++k){ const double d = c[k]-dr; var += p[k]*(d*d); }
  const double un = sqrt(var);
  int cnt = 0;
  #pragma unroll
  for (int k=1;k<BN;++k) cnt += (dr >= edges[(b*(BN+1)+k)*HW + r]) ? 1 : 0;
  const double etop = edges[(b*(BN+1)+BN)*HW + r];
  const int label = (dr >= etop) ? 0 : cnt;
  double csv = c[0];
  #pragma unroll
  for (int k=1;k<BN;++k) csv = (label==k) ? c[k] : csv;
  out[((0*6+it)*NB + b)*HW + r] = (float)dr;
  out[((1*6+it)*NB + b)*HW + r] = (float)csv;
  out[((2*6+it)*NB + b)*HW + r] = (float)un;
  const double start = dr - 0.5*un > 0.0 ? dr - 0.5*un : 0.0;
  const double step = un * (1.0/BN);
  double e = start;
  double prev = e < 0.0 ? 0.0 : (e > 80.0 ? 80.0 : e);
  edges[(b*(BN+1)+0)*HW + r] = prev;
  #pragma unroll
  for (int k=1;k<=BN;++k){
    e = e + step;
    const double ec = e < 0.0 ? 0.0 : (e > 80.0 ? 80.0 : e);
    edges[(b*(BN+1)+k)*HW + r] = ec;
    cdp[((size_t)b*BN + (k-1))*PHW + pr] = 0.5*(prev + ec);
    prev = ec;
  }
}

// ----------------------------------------------------------- launcher ----
extern "C" void kernel_launch(void* const* d_in, const int* in_sizes, int n_in,
                              void* d_out, int out_size, void* d_ws, size_t ws_size,
                              hipStream_t stream){
  const float* ctx = (const float*)d_in[1];
  const float* gh  = (const float*)d_in[2];
  const float *e1w=(const float*)d_in[3],  *e1b=(const float*)d_in[4];
  const float *e2w=(const float*)d_in[5],  *e2b=(const float*)d_in[6];
  const float *e3w=(const float*)d_in[7],  *e3b=(const float*)d_in[8];
  const float *e4w=(const float*)d_in[9],  *e4b=(const float*)d_in[10];
  const float *z1w=(const float*)d_in[11], *z1b=(const float*)d_in[12];
  const float *r1w=(const float*)d_in[13], *r1b=(const float*)d_in[14];
  const float *q1w=(const float*)d_in[15], *q1b=(const float*)d_in[16];
  const float *z2w=(const float*)d_in[17], *z2b=(const float*)d_in[18];
  const float *r2w=(const float*)d_in[19], *r2b=(const float*)d_in[20];
  const float *q2w=(const float*)d_in[21], *q2b=(const float*)d_in[22];
  const float *p1w=(const float*)d_in[23], *p1b=(const float*)d_in[24];
  const float *p2w=(const float*)d_in[25], *p2b=(const float*)d_in[26];
  float* out = (float*)d_out;

  // f64 region: edges (unpadded), cdp (padded)
  double* edges = (double*)d_ws;                        // NB*17*HW
  double* cdp   = edges + (size_t)NB*(BN+1)*HW;         // NB*16*PHW
  // f32 padded planes (halo pre-zeroed each launch), then unpadded + weights
  float* fb    = (float*)(cdp + (size_t)NB*BN*PHW);
  float* hp    = fb;                                    // NB*128*PHW
  float* d4p   = hp    + (size_t)NB*HD *PHW;            // NB*256*PHW
  float* bufAp = d4p   + (size_t)NB*OCH*PHW;            // NB*128*PHW
  float* bufBp = bufAp + (size_t)NB*HD *PHW;            // NB*128*PHW
  float* ctxp  = bufBp + (size_t)NB*HD *PHW;            // NB*192*PHW
  float* lgtsp = ctxp  + (size_t)NB*CDC*PHW;            // NB*16*PHW
  const size_t npad32 = (size_t)NB*(HD+OCH+HD+HD+CDC+BN)*PHW;
  float* qx   = lgtsp + (size_t)NB*BN*PHW;              // NB*128*HW (unpadded)
  float* wp   = qx + (size_t)NB*HD*HW;
  float* we1 = wp;              wp += (size_t)HD*16*49;
  float* we2 = wp;              wp += (size_t)HD*HD*9;
  float* we3 = wp;              wp += (size_t)HD*HD*9;
  float* we4 = wp;              wp += (size_t)OCH*HD*9;
  float* wz1 = wp;              wp += (size_t)HD*GC*5;
  float* wr1 = wp;              wp += (size_t)HD*GC*5;
  float* wq1 = wp;              wp += (size_t)HD*GC*5;
  float* wz2 = wp;              wp += (size_t)HD*GC*5;
  float* wr2 = wp;              wp += (size_t)HD*GC*5;
  float* wq2 = wp;              wp += (size_t)HD*GC*5;
  float* wp1 = wp;              wp += (size_t)HD*HD*9;
  float* wp2 = wp;              wp += (size_t)16*HD*9;

  const dim3 blk(256);

  k_zero32<<<dim3(2048), blk, 0, stream>>>(fb, npad32);
  k_zero64<<<dim3(1024), blk, 0, stream>>>(cdp, (size_t)NB*BN*PHW);

  #define XP(src,dst,Cout_,CIN_,TAPS_) { const int n=(Cout_)*(CIN_)*(TAPS_); \
    k_wxpose<<<dim3((n+255)/256), blk, 0, stream>>>(src, dst, Cout_, CIN_, TAPS_, n); }
  XP(e1w, we1, HD, 16, 49); XP(e2w, we2, HD, HD, 9); XP(e3w, we3, HD, HD, 9);
  XP(e4w, we4, OCH, HD, 9);
  XP(z1w, wz1, HD, GC, 5); XP(r1w, wr1, HD, GC, 5); XP(q1w, wq1, HD, GC, 5);
  XP(z2w, wz2, HD, GC, 5); XP(r2w, wr2, HD, GC, 5); XP(q2w, wq2, HD, GC, 5);
  XP(p1w, wp1, HD, HD, 9); XP(p2w, wp2, 16, HD, 9);
  #undef XP

  k_pad<<<dim3((NB*CDC*HW+255)/256), blk, 0, stream>>>(ctx, ctxp, NB*CDC);
  k_init<<<dim3((NB*HD*HW+255)/256), blk, 0, stream>>>(gh, hp, edges, cdp);

  const int G8 = GXP*8, G4 = GXP*4, G1 = GXP;
  const int GZ = 2048;                 // tail-packed zrx grid
  const int PXB = BHW/256;

  for (int it=0; it<6; ++it){
    k_e1        <<<dim3(G4), blk, 0, stream>>>(cdp,   we1, e1b, bufAp);
    k_fc3<8,4,1><<<dim3(G4), blk, 0, stream>>>(bufAp, we2, e2b, bufBp, HD);
    k_fc3<8,4,1><<<dim3(G4), blk, 0, stream>>>(bufBp, we3, e3b, bufAp, HD);
    k_fc3<8,8,1><<<dim3(G8), blk, 0, stream>>>(bufAp, we4, e4b, d4p,  OCH);
    // horizontal GRU
    k_zrx<0><<<dim3(GZ), blk, 0, stream>>>(hp, d4p, ctxp, wz1, wr1, wq1,
                                           z1b, r1b, q1b, bufAp, bufBp, qx);
    k_qh <0><<<dim3(G4), blk, 0, stream>>>(bufBp, wq1, qx, bufAp, hp);
    // vertical GRU
    k_zrx<1><<<dim3(GZ), blk, 0, stream>>>(hp, d4p, ctxp, wz2, wr2, wq2,
                                           z2b, r2b, q2b, bufAp, bufBp, qx);
    k_qh <1><<<dim3(G4), blk, 0, stream>>>(bufBp, wq2, qx, bufAp, hp);
    // PHead
    k_fc3<8,4,1><<<dim3(G4), blk, 0, stream>>>(hp,    wp1, p1b, bufAp, HD);
    k_fc3<4,1,0><<<dim3(G1), blk, 0, stream>>>(bufAp, wp2, p2b, lgtsp, 16);
    k_stats<<<dim3(PXB), blk, 0, stream>>>(lgtsp, edges, cdp, out, it);
  }
}

// Round 8
// 25149.782 us; speedup vs baseline: 1.4683x; 1.4683x over previous
//
#include <hip/hip_runtime.h>
#include <hip/hip_bf16.h>

// IEBins forward. Round 19: FULL REVERT to r17 + dwordx4 weight loads.
// r18 post-mortem: tail-packing FAILED (I-cache thrash from dual sweep
// bodies + staggered waves re-broke temporal locality -> FETCH 4.3GB).
// Scheduling space is CLOSED: per-wave work is VGPR-pinned (f64 masters),
// 9728 waves / 8192 slots is invariant; r14/r15/r18 all catastrophic.
// Recalibrated model: gfx950 v_pk_fma_f32 is FLOP-neutral (157.3 TF spec
// = plain-FMA rate) -> payload = 48 cy/ch-step of 66 measured -> in-round
// ~73% of the f32 issue wall; overhead only ~18cy. Last cheap probe:
// weight loads widened to dwordx4 (1 per gate per step at NACC=4) in case
// they are vector-form (r12's null was on the old px-packed structure).
// Identical bytes -> identical fma operands; FROZEN r9 order untouched
// (tap-outer, seg H,d4,ctx, chunk-32 f32 partials -> f64 masters,
// channels ascending). absmax must stay 1.0.

#define HD  128
#define CDC 192
#define BN  16
#define OCH 256
#define GC  576
#define NB  2
#define HH  120
#define WW  160
#define HW  (HH*WW)
#define BHW (NB*HW)
#define PXT (BHW/128)          // 300 pixel tiles of 128 px
#define GXP (((PXT+7)/8)*8)    // 304 padded
#define TPX (GXP/8)            // 38 tiles per XCD slab
// padded plane geometry: 3 halo rows top/bottom, 4 cols left/right
#define PWW 168
#define PHH 126
#define PHW (PWW*PHH)          // 21168
#define POFF(y,x) (((y)+3)*PWW + (x) + 4)

__device__ __forceinline__ float2 ldf2(const float* p){ return *(const float2*)p; }
__device__ __forceinline__ void stf2(float* p, float a, float b){
  *(float2*)p = make_float2(a,b);
}

// packed pair type (4B-aligned loads ok on gfx9+).
typedef float f2 __attribute__((ext_vector_type(2), aligned(4)));
typedef float f4 __attribute__((ext_vector_type(4), aligned(16)));
// uniform base + unsigned 32-bit offset -> global_load saddr form.
__device__ __forceinline__ f2 ldpo(const float* __restrict__ base, const unsigned off){
  return *(const f2*)(base + off);
}
// weight row load: NP out-ch pairs via 16B dwordx4 chunks (16B-aligned by
// construction: ow0 mult of NACC, all strides mult of 4 floats).
template<int NP>
__device__ __forceinline__ void ldwn(const float* __restrict__ p, f2* w){
  #pragma unroll
  for (int k=0;k<NP;k+=2){
    const f4 v = *(const f4*)(p + 2*k);
    w[k]   = f2{v.x, v.y};
    w[k+1] = f2{v.z, v.w};
  }
}

// packed FMA on two out-channels: a.{lo,hi} += v * w.{lo,hi}
__device__ __forceinline__ void pkfma2(f2& a, const f2 v, const f2 w){
  a = __builtin_elementwise_fma(v, w, a);
}

// ---------------------------------------------------------------- zero ----
__global__ __launch_bounds__(256) void k_zero32(float* __restrict__ p, const size_t n){
  const size_t i = (size_t)blockIdx.x*256 + threadIdx.x;
  for (size_t k=i; k<n; k += (size_t)gridDim.x*256) p[k] = 0.f;
}
__global__ __launch_bounds__(256) void k_zero64(double* __restrict__ p, const size_t n){
  const size_t i = (size_t)blockIdx.x*256 + threadIdx.x;
  for (size_t k=i; k<n; k += (size_t)gridDim.x*256) p[k] = 0.0;
}

// ------------------------------------------------------------- pad ctx ----
__global__ __launch_bounds__(256) void k_pad(const float* __restrict__ src,
        float* __restrict__ dst, const int nplanes){
  const int i = blockIdx.x*256 + threadIdx.x;
  if (i >= nplanes*HW) return;
  const int bc = i / HW, r = i - bc*HW;
  const int y = r / WW, x = r - y*WW;
  dst[(size_t)bc*PHW + POFF(y,x)] = src[i];
}

// ---------------------------------------------------------------- init ----
__global__ __launch_bounds__(256) void k_init(const float* __restrict__ gh,
        float* __restrict__ h, double* __restrict__ edges, double* __restrict__ cdp){
  const int i = blockIdx.x*256 + threadIdx.x;
  const int nh = NB*HD*HW;
  if (i < nh){
    const int bc = i / HW, r = i - bc*HW;
    const int y = r / WW, x = r - y*WW;
    h[(size_t)bc*PHW + POFF(y,x)] = gh[i];
  }
  if (i < BHW){
    const int b = i / HW, r = i - b*HW;
    const int y = r / WW, x = r - y*WW;
    const int pr = POFF(y,x);
    double e = 0.0;
    #pragma unroll
    for (int k=0;k<BN;++k){
      edges[(b*(BN+1)+k)*HW + r] = e;
      cdp[((size_t)b*BN+k)*PHW + pr] = e + 2.5;
      e += 5.0;
    }
    edges[(b*(BN+1)+BN)*HW + r] = e;   // 80
  }
}

// ------------------------------------------------- weight transpose ------
// w[o][c][tap] f32  ->  wt[(c*TAPS+t)*Cout + o]
__global__ __launch_bounds__(256) void k_wxpose(const float* __restrict__ w,
        float* __restrict__ wt, const int Cout, const int CIN, const int TAPS,
        const int n){
  const int i = blockIdx.x*256 + threadIdx.x;
  if (i >= n) return;
  const int ct = CIN*TAPS;
  const int o = i / ct;
  const int rem = i - o*ct;
  const int c = rem / TAPS;
  const int t = rem - c*TAPS;
  wt[((size_t)c*TAPS + t)*Cout + o] = w[i];
}

// ------------------------------------------- XCD-aware block decode ------
template<int GY>
__device__ __forceinline__ bool blk_decode(int& xs, int& yg){
  const int id  = blockIdx.x;
  const int xcd = id & 7;
  const int s   = id >> 3;
  yg = s & (GY-1);
  const int k = s / GY;
  xs = xcd*TPX + k;
  return xs < PXT;
}

// pair-pixel decode: lane -> 2 adjacent px (x even)
__device__ __forceinline__ void pair_decode(const int xs, int& b, int& r0, int& po){
  const int lane = threadIdx.x & 63;
  const int pb = xs*128;
  b = pb / HW;
  r0 = pb - b*HW + 2*lane;
  const int y = r0 / WW, x = r0 - y*WW;
  po = POFF(y,x);
}

// ------------------------------------------------ e1: 7x7, 16ch, f64 in --
// tap outer, single 16-ch f32 chunk (r9 order); out-ch-pair packed FMA.
__global__ __launch_bounds__(256) void k_e1(const double* __restrict__ cdp,
        const float* __restrict__ wt, const float* __restrict__ bias,
        float* __restrict__ out){
  const int NACC = 8, NP = NACC/2;
  int xs, yg;
  if (!blk_decode<4>(xs, yg)) return;
  const int wvu = __builtin_amdgcn_readfirstlane((int)(threadIdx.x >> 6));
  const int ow0 = (yg*4 + wvu)*NACC;
  int b, r0, po;
  pair_decode(xs, b, r0, po);
  double acc[2][NACC];
  #pragma unroll
  for (int j=0;j<NACC;++j){
    const double bj = (double)bias[ow0+j];
    acc[0][j]=bj; acc[1][j]=bj;
  }
  const double* inb = cdp + (size_t)b*16*PHW;
  #pragma unroll 1
  for (int t=0;t<49;++t){
    const unsigned pot = (unsigned)(po + (t/7 - 3)*PWW + (t%7 - 3));
    f2 ca[2][NP];
    #pragma unroll
    for (int p=0;p<NP;++p){ ca[0][p]=f2{0.f,0.f}; ca[1][p]=f2{0.f,0.f}; }
    const float* wr = wt + (size_t)t*HD + ow0;
    #pragma unroll 4
    for (int c=0;c<16;++c){
      const double* pp = inb + (size_t)c*PHW;      // uniform base
      const float v0 = (float)pp[pot];
      const float v1 = (float)pp[pot+1u];
      const f2 v00 = {v0, v0};
      const f2 v11 = {v1, v1};
      f2 wp_[NP];
      ldwn<NP>(wr, wp_);
      #pragma unroll
      for (int p=0;p<NP;++p){
        pkfma2(ca[0][p], v00, wp_[p]);
        pkfma2(ca[1][p], v11, wp_[p]);
      }
      wr += (size_t)49*HD;
    }
    #pragma unroll
    for (int p=0;p<NP;++p){
      acc[0][2*p]  +=(double)ca[0][p].x; acc[0][2*p+1]+=(double)ca[0][p].y;
      acc[1][2*p]  +=(double)ca[1][p].x; acc[1][2*p+1]+=(double)ca[1][p].y;
    }
  }
  #pragma unroll
  for (int j=0;j<NACC;++j){
    double v0 = acc[0][j]; v0 = v0>0.0?v0:0.0;
    double v1 = acc[1][j]; v1 = v1>0.0?v1:0.0;
    stf2(out + ((size_t)b*HD + ow0 + j)*PHW + po, (float)v0, (float)v1);
  }
}

// ------------------------------------------------ 3x3 conv, 128ch, f32 ---
// r9 fconv order: tap OUTER, chunk-32 inner; out-ch-pair packed FMA.
template<int NACC,int GY,int ACT>
__global__ __launch_bounds__(256) void k_fc3(const float* __restrict__ in,
        const float* __restrict__ wt, const float* __restrict__ bias,
        float* __restrict__ out, const int Cout){
  const int NP = NACC/2;
  int xs, yg;
  if (!blk_decode<GY>(xs, yg)) return;
  const int wvu = __builtin_amdgcn_readfirstlane((int)(threadIdx.x >> 6));
  const int ow0 = (yg*4 + wvu)*NACC;
  int b, r0, po;
  pair_decode(xs, b, r0, po);
  double acc[2][NACC];
  #pragma unroll
  for (int j=0;j<NACC;++j){
    const double bj = (double)bias[ow0+j];
    acc[0][j]=bj; acc[1][j]=bj;
  }
  const float* inb = in + (size_t)b*128*PHW;
  #pragma unroll 1
  for (int t=0;t<9;++t){
    const unsigned pot = (unsigned)(po + (t/3 - 1)*PWW + (t%3 - 1));
    #pragma unroll 1
    for (int c0=0;c0<128;c0+=32){
      f2 ca[2][NP];
      #pragma unroll
      for (int p=0;p<NP;++p){ ca[0][p]=f2{0.f,0.f}; ca[1][p]=f2{0.f,0.f}; }
      const float* wr = wt + ((size_t)c0*9 + t)*Cout + ow0;
      #pragma unroll 8
      for (int c=0;c<32;++c){
        const f2 v = ldpo(inb + (size_t)(c0+c)*PHW, pot);
        const f2 v00 = {v.x, v.x};
        const f2 v11 = {v.y, v.y};
        f2 wp_[NP];
        ldwn<NP>(wr, wp_);
        #pragma unroll
        for (int p=0;p<NP;++p){
          pkfma2(ca[0][p], v00, wp_[p]);
          pkfma2(ca[1][p], v11, wp_[p]);
        }
        wr += (size_t)9*Cout;
      }
      #pragma unroll
      for (int p=0;p<NP;++p){
        acc[0][2*p]  +=(double)ca[0][p].x; acc[0][2*p+1]+=(double)ca[0][p].y;
        acc[1][2*p]  +=(double)ca[1][p].x; acc[1][2*p+1]+=(double)ca[1][p].y;
      }
    }
  }
  #pragma unroll
  for (int j=0;j<NACC;++j){
    double v0 = acc[0][j], v1 = acc[1][j];
    if (ACT==1){ v0 = v0>0.0?v0:0.0; v1 = v1>0.0?v1:0.0; }
    stf2(out + ((size_t)b*Cout + ow0 + j)*PHW + po, (float)v0, (float)v1);
  }
}

// ------------------------------------------- GRU segments (r9 order) -----
// Two-gate (z,r); chunk-32 f32; out-ch-pair packed FMA; unroll 4.
template<int C,int NACC>
__device__ __forceinline__ void seg2(const float* __restrict__ plane, const unsigned pot,
    const float* __restrict__ wz0, const float* __restrict__ wr0,
    double az[2][NACC], double ar[2][NACC]){
  const int NP = NACC/2;
  #pragma unroll 1
  for (int c0=0;c0<C;c0+=32){
    f2 cz[2][NP], cr[2][NP];
    #pragma unroll
    for (int p=0;p<NP;++p){
      cz[0][p]=f2{0.f,0.f}; cz[1][p]=f2{0.f,0.f};
      cr[0][p]=f2{0.f,0.f}; cr[1][p]=f2{0.f,0.f};
    }
    const float* wz = wz0 + (size_t)c0*5*HD;
    const float* wr = wr0 + (size_t)c0*5*HD;
    #pragma unroll 4
    for (int c=0;c<32;++c){
      const f2 v = ldpo(plane + (size_t)(c0+c)*PHW, pot);
      const f2 v00 = {v.x, v.x};
      const f2 v11 = {v.y, v.y};
      f2 wzp[NP], wrp[NP];
      ldwn<NP>(wz, wzp);
      ldwn<NP>(wr, wrp);
      #pragma unroll
      for (int p=0;p<NP;++p){
        pkfma2(cz[0][p], v00, wzp[p]); pkfma2(cz[1][p], v11, wzp[p]);
        pkfma2(cr[0][p], v00, wrp[p]); pkfma2(cr[1][p], v11, wrp[p]);
      }
      wz += 5*HD; wr += 5*HD;
    }
    #pragma unroll
    for (int p=0;p<NP;++p){
      az[0][2*p]+=(double)cz[0][p].x; az[0][2*p+1]+=(double)cz[0][p].y;
      az[1][2*p]+=(double)cz[1][p].x; az[1][2*p+1]+=(double)cz[1][p].y;
      ar[0][2*p]+=(double)cr[0][p].x; ar[0][2*p+1]+=(double)cr[0][p].y;
      ar[1][2*p]+=(double)cr[1][p].x; ar[1][2*p+1]+=(double)cr[1][p].y;
    }
  }
}
// Three-gate (z,r,qx).
template<int C,int NACC>
__device__ __forceinline__ void seg3(const float* __restrict__ plane, const unsigned pot,
    const float* __restrict__ wz0, const float* __restrict__ wr0,
    const float* __restrict__ wq0,
    double az[2][NACC], double ar[2][NACC], double aq[2][NACC]){
  const int NP = NACC/2;
  #pragma unroll 1
  for (int c0=0;c0<C;c0+=32){
    f2 cz[2][NP], cr[2][NP], cq[2][NP];
    #pragma unroll
    for (int p=0;p<NP;++p){
      cz[0][p]=f2{0.f,0.f}; cz[1][p]=f2{0.f,0.f};
      cr[0][p]=f2{0.f,0.f}; cr[1][p]=f2{0.f,0.f};
      cq[0][p]=f2{0.f,0.f}; cq[1][p]=f2{0.f,0.f};
    }
    const float* wz = wz0 + (size_t)c0*5*HD;
    const float* wr = wr0 + (size_t)c0*5*HD;
    const float* wq = wq0 + (size_t)c0*5*HD;
    #pragma unroll 4
    for (int c=0;c<32;++c){
      const f2 v = ldpo(plane + (size_t)(c0+c)*PHW, pot);
      const f2 v00 = {v.x, v.x};
      const f2 v11 = {v.y, v.y};
      f2 wzp[NP], wrp[NP], wqp[NP];
      ldwn<NP>(wz, wzp);
      ldwn<NP>(wr, wrp);
      ldwn<NP>(wq, wqp);
      #pragma unroll
      for (int p=0;p<NP;++p){
        pkfma2(cz[0][p], v00, wzp[p]); pkfma2(cz[1][p], v11, wzp[p]);
        pkfma2(cr[0][p], v00, wrp[p]); pkfma2(cr[1][p], v11, wrp[p]);
        pkfma2(cq[0][p], v00, wqp[p]); pkfma2(cq[1][p], v11, wqp[p]);
      }
      wz += 5*HD; wr += 5*HD; wq += 5*HD;
    }
    #pragma unroll
    for (int p=0;p<NP;++p){
      az[0][2*p]+=(double)cz[0][p].x; az[0][2*p+1]+=(double)cz[0][p].y;
      az[1][2*p]+=(double)cz[1][p].x; az[1][2*p+1]+=(double)cz[1][p].y;
      ar[0][2*p]+=(double)cr[0][p].x; ar[0][2*p+1]+=(double)cr[0][p].y;
      ar[1][2*p]+=(double)cr[1][p].x; ar[1][2*p+1]+=(double)cr[1][p].y;
      aq[0][2*p]+=(double)cq[0][p].x; aq[0][2*p+1]+=(double)cq[0][p].y;
      aq[1][2*p]+=(double)cq[1][p].x; aq[1][2*p+1]+=(double)cq[1][p].y;
    }
  }
}
// One-gate (qh); unroll 8.
template<int C,int NACC>
__device__ __forceinline__ void seg1(const float* __restrict__ plane, const unsigned pot,
    const float* __restrict__ wq0, double aq[2][NACC]){
  const int NP = NACC/2;
  #pragma unroll 1
  for (int c0=0;c0<C;c0+=32){
    f2 cq[2][NP];
    #pragma unroll
    for (int p=0;p<NP;++p){ cq[0][p]=f2{0.f,0.f}; cq[1][p]=f2{0.f,0.f}; }
    const float* wq = wq0 + (size_t)c0*5*HD;
    #pragma unroll 8
    for (int c=0;c<32;++c){
      const f2 v = ldpo(plane + (size_t)(c0+c)*PHW, pot);
      const f2 v00 = {v.x, v.x};
      const f2 v11 = {v.y, v.y};
      f2 wqp[NP];
      ldwn<NP>(wq, wqp);
      #pragma unroll
      for (int p=0;p<NP;++p){
        pkfma2(cq[0][p], v00, wqp[p]);
        pkfma2(cq[1][p], v11, wqp[p]);
      }
      wq += 5*HD;
    }
    #pragma unroll
    for (int p=0;p<NP;++p){
      aq[0][2*p]+=(double)cq[0][p].x; aq[0][2*p+1]+=(double)cq[0][p].y;
      aq[1][2*p]+=(double)cq[1][p].x; aq[1][2*p+1]+=(double)cq[1][p].y;
    }
  }
}

// Fused z,r,qx. NACC=4, GY=8. Tap OUTER (r9 order).
template<int VERT>
__global__ __launch_bounds__(256) void k_zrx(
    const float* __restrict__ h, const float* __restrict__ d4,
    const float* __restrict__ ctxp,
    const float* __restrict__ wtz, const float* __restrict__ wtr,
    const float* __restrict__ wtq,
    const float* __restrict__ bz, const float* __restrict__ br,
    const float* __restrict__ bq,
    float* __restrict__ zg, float* __restrict__ rgh, float* __restrict__ qx){
  const int NACC = 4;
  int xs, yg;
  if (!blk_decode<8>(xs, yg)) return;
  const int wvu = __builtin_amdgcn_readfirstlane((int)(threadIdx.x >> 6));
  const int ow0 = (yg*4 + wvu)*NACC;          // 0..124
  int b, r0, po;
  pair_decode(xs, b, r0, po);
  double az[2][NACC], ar[2][NACC], aq[2][NACC];
  #pragma unroll
  for (int j=0;j<NACC;++j){
    const double bzj=(double)bz[ow0+j], brj=(double)br[ow0+j], bqj=(double)bq[ow0+j];
    az[0][j]=bzj; az[1][j]=bzj; ar[0][j]=brj; ar[1][j]=brj; aq[0][j]=bqj; aq[1][j]=bqj;
  }
  const float* hb = h   + (size_t)b*HD *PHW;
  const float* db = d4  + (size_t)b*OCH*PHW;
  const float* cb = ctxp+ (size_t)b*CDC*PHW;
  #pragma unroll 1
  for (int t=0;t<5;++t){
    const unsigned pot = (unsigned)(po + (VERT ? (t-2)*PWW : (t-2)));
    seg2<HD ,NACC>(hb, pot, wtz + (size_t)t*HD + ow0,
                            wtr + (size_t)t*HD + ow0, az, ar);
    seg3<OCH,NACC>(db, pot, wtz + ((size_t)HD*5 + t)*HD + ow0,
                            wtr + ((size_t)HD*5 + t)*HD + ow0,
                            wtq + ((size_t)HD*5 + t)*HD + ow0, az, ar, aq);
    seg3<CDC,NACC>(cb, pot, wtz + ((size_t)(HD+OCH)*5 + t)*HD + ow0,
                            wtr + ((size_t)(HD+OCH)*5 + t)*HD + ow0,
                            wtq + ((size_t)(HD+OCH)*5 + t)*HD + ow0, az, ar, aq);
  }
  #pragma unroll
  for (int j=0;j<NACC;++j){
    const size_t pp = ((size_t)b*HD + ow0 + j)*PHW + po;
    const float2 hv = ldf2(h + pp);
    const double z0 = 1.0/(1.0+exp(-az[0][j])), z1 = 1.0/(1.0+exp(-az[1][j]));
    const double g0 = (1.0/(1.0+exp(-ar[0][j]))) * (double)hv.x;
    const double g1 = (1.0/(1.0+exp(-ar[1][j]))) * (double)hv.y;
    stf2(zg  + pp, (float)z0, (float)z1);
    stf2(rgh + pp, (float)g0, (float)g1);
    stf2(qx + ((size_t)b*HD + ow0 + j)*HW + r0, (float)aq[0][j], (float)aq[1][j]);
  }
}

// q over rgh (128 ch) + hidden update. NACC=8, GY=4. Tap OUTER.
template<int VERT>
__global__ __launch_bounds__(256) void k_qh(
    const float* __restrict__ rgh, const float* __restrict__ wtq,
    const float* __restrict__ qx, const float* __restrict__ zg,
    float* __restrict__ h){
  const int NACC = 8;
  int xs, yg;
  if (!blk_decode<4>(xs, yg)) return;
  const int wvu = __builtin_amdgcn_readfirstlane((int)(threadIdx.x >> 6));
  const int ow0 = (yg*4 + wvu)*NACC;
  int b, r0, po;
  pair_decode(xs, b, r0, po);
  double aq[2][NACC];
  #pragma unroll
  for (int j=0;j<NACC;++j){
    const float2 q0 = ldf2(qx + ((size_t)b*HD + ow0 + j)*HW + r0);
    aq[0][j] = (double)q0.x; aq[1][j] = (double)q0.y;
  }
  const float* gb = rgh + (size_t)b*HD*PHW;
  #pragma unroll 1
  for (int t=0;t<5;++t){
    const unsigned pot = (unsigned)(po + (VERT ? (t-2)*PWW : (t-2)));
    seg1<HD,NACC>(gb, pot, wtq + (size_t)t*HD + ow0, aq);
  }
  #pragma unroll
  for (int j=0;j<NACC;++j){
    const size_t pp = ((size_t)b*HD + ow0 + j)*PHW + po;
    const float2 zv = ldf2(zg + pp);
    const float2 hv = ldf2(h  + pp);
    const double z0=(double)zv.x, z1=(double)zv.y;
    const double n0 = (1.0-z0)*(double)hv.x + z0*tanh(aq[0][j]);
    const double n1 = (1.0-z1)*(double)hv.y + z1*tanh(aq[1][j]);
    stf2(h + pp, (float)n0, (float)n1);
  }
}

// ------------------- softmax + depth_r + unc + label + cs + bin update ----
__global__ __launch_bounds__(256) void k_stats(const float* __restrict__ lg,
    double* __restrict__ edges, double* __restrict__ cdp, float* __restrict__ out,
    const int it){
  const int px = blockIdx.x*256 + threadIdx.x;
  const int b = px / HW, r = px - b*HW;
  const int y = r / WW, x = r - y*WW;
  const int pr = POFF(y,x);
  double l[BN], p[BN], c[BN];
  double m = -1e300;
  #pragma unroll
  for (int k=0;k<BN;++k){ l[k] = (double)lg[((size_t)b*BN+k)*PHW + pr]; m = l[k]>m?l[k]:m; }
  double s = 0.0;
  #pragma unroll
  for (int k=0;k<BN;++k){ p[k] = exp(l[k]-m); s += p[k]; }
  double dr = 0.0;
  #pragma unroll
  for (int k=0;k<BN;++k){ c[k] = cdp[((size_t)b*BN+k)*PHW + pr]; p[k] = p[k]/s; dr += p[k]*c[k]; }
  double var = 0.0;
  #pragma unroll
  for (int k=0;k<BN;++k){ const double d = c[k]-dr; var += p[k]*(d*d); }
  const double un = sqrt(var);
  int cnt = 0;
  #pragma unroll
  for (int k=1;k<BN;++k) cnt += (dr >= edges[(b*(BN+1)+k)*HW + r]) ? 1 : 0;
  const double etop = edges[(b*(BN+1)+BN)*HW + r];
  const int label = (dr >= etop) ? 0 : cnt;
  double csv = c[0];
  #pragma unroll
  for (int k=1;k<BN;++k) csv = (label==k) ? c[k] : csv;
  out[((0*6+it)*NB + b)*HW + r] = (float)dr;
  out[((1*6+it)*NB + b)*HW + r] = (float)csv;
  out[((2*6+it)*NB + b)*HW + r] = (float)un;
  const double start = dr - 0.5*un > 0.0 ? dr - 0.5*un : 0.0;
  const double step = un * (1.0/BN);
  double e = start;
  double prev = e < 0.0 ? 0.0 : (e > 80.0 ? 80.0 : e);
  edges[(b*(BN+1)+0)*HW + r] = prev;
  #pragma unroll
  for (int k=1;k<=BN;++k){
    e = e + step;
    const double ec = e < 0.0 ? 0.0 : (e > 80.0 ? 80.0 : e);
    edges[(b*(BN+1)+k)*HW + r] = ec;
    cdp[((size_t)b*BN + (k-1))*PHW + pr] = 0.5*(prev + ec);
    prev = ec;
  }
}

// ----------------------------------------------------------- launcher ----
extern "C" void kernel_launch(void* const* d_in, const int* in_sizes, int n_in,
                              void* d_out, int out_size, void* d_ws, size_t ws_size,
                              hipStream_t stream){
  const float* ctx = (const float*)d_in[1];
  const float* gh  = (const float*)d_in[2];
  const float *e1w=(const float*)d_in[3],  *e1b=(const float*)d_in[4];
  const float *e2w=(const float*)d_in[5],  *e2b=(const float*)d_in[6];
  const float *e3w=(const float*)d_in[7],  *e3b=(const float*)d_in[8];
  const float *e4w=(const float*)d_in[9],  *e4b=(const float*)d_in[10];
  const float *z1w=(const float*)d_in[11], *z1b=(const float*)d_in[12];
  const float *r1w=(const float*)d_in[13], *r1b=(const float*)d_in[14];
  const float *q1w=(const float*)d_in[15], *q1b=(const float*)d_in[16];
  const float *z2w=(const float*)d_in[17], *z2b=(const float*)d_in[18];
  const float *r2w=(const float*)d_in[19], *r2b=(const float*)d_in[20];
  const float *q2w=(const float*)d_in[21], *q2b=(const float*)d_in[22];
  const float *p1w=(const float*)d_in[23], *p1b=(const float*)d_in[24];
  const float *p2w=(const float*)d_in[25], *p2b=(const float*)d_in[26];
  float* out = (float*)d_out;

  // f64 region: edges (unpadded), cdp (padded)
  double* edges = (double*)d_ws;                        // NB*17*HW
  double* cdp   = edges + (size_t)NB*(BN+1)*HW;         // NB*16*PHW
  // f32 padded planes (halo pre-zeroed each launch), then unpadded + weights
  float* fb    = (float*)(cdp + (size_t)NB*BN*PHW);
  float* hp    = fb;                                    // NB*128*PHW
  float* d4p   = hp    + (size_t)NB*HD *PHW;            // NB*256*PHW
  float* bufAp = d4p   + (size_t)NB*OCH*PHW;            // NB*128*PHW
  float* bufBp = bufAp + (size_t)NB*HD *PHW;            // NB*128*PHW
  float* ctxp  = bufBp + (size_t)NB*HD *PHW;            // NB*192*PHW
  float* lgtsp = ctxp  + (size_t)NB*CDC*PHW;            // NB*16*PHW
  const size_t npad32 = (size_t)NB*(HD+OCH+HD+HD+CDC+BN)*PHW;
  float* qx   = lgtsp + (size_t)NB*BN*PHW;              // NB*128*HW (unpadded)
  float* wp   = qx + (size_t)NB*HD*HW;
  float* we1 = wp;              wp += (size_t)HD*16*49;
  float* we2 = wp;              wp += (size_t)HD*HD*9;
  float* we3 = wp;              wp += (size_t)HD*HD*9;
  float* we4 = wp;              wp += (size_t)OCH*HD*9;
  float* wz1 = wp;              wp += (size_t)HD*GC*5;
  float* wr1 = wp;              wp += (size_t)HD*GC*5;
  float* wq1 = wp;              wp += (size_t)HD*GC*5;
  float* wz2 = wp;              wp += (size_t)HD*GC*5;
  float* wr2 = wp;              wp += (size_t)HD*GC*5;
  float* wq2 = wp;              wp += (size_t)HD*GC*5;
  float* wp1 = wp;              wp += (size_t)HD*HD*9;
  float* wp2 = wp;              wp += (size_t)16*HD*9;

  const dim3 blk(256);

  k_zero32<<<dim3(2048), blk, 0, stream>>>(fb, npad32);
  k_zero64<<<dim3(1024), blk, 0, stream>>>(cdp, (size_t)NB*BN*PHW);

  #define XP(src,dst,Cout_,CIN_,TAPS_) { const int n=(Cout_)*(CIN_)*(TAPS_); \
    k_wxpose<<<dim3((n+255)/256), blk, 0, stream>>>(src, dst, Cout_, CIN_, TAPS_, n); }
  XP(e1w, we1, HD, 16, 49); XP(e2w, we2, HD, HD, 9); XP(e3w, we3, HD, HD, 9);
  XP(e4w, we4, OCH, HD, 9);
  XP(z1w, wz1, HD, GC, 5); XP(r1w, wr1, HD, GC, 5); XP(q1w, wq1, HD, GC, 5);
  XP(z2w, wz2, HD, GC, 5); XP(r2w, wr2, HD, GC, 5); XP(q2w, wq2, HD, GC, 5);
  XP(p1w, wp1, HD, HD, 9); XP(p2w, wp2, 16, HD, 9);
  #undef XP

  k_pad<<<dim3((NB*CDC*HW+255)/256), blk, 0, stream>>>(ctx, ctxp, NB*CDC);
  k_init<<<dim3((NB*HD*HW+255)/256), blk, 0, stream>>>(gh, hp, edges, cdp);

  const int G8 = GXP*8, G4 = GXP*4, G1 = GXP;
  const int PXB = BHW/256;

  for (int it=0; it<6; ++it){
    k_e1        <<<dim3(G4), blk, 0, stream>>>(cdp,   we1, e1b, bufAp);
    k_fc3<8,4,1><<<dim3(G4), blk, 0, stream>>>(bufAp, we2, e2b, bufBp, HD);
    k_fc3<8,4,1><<<dim3(G4), blk, 0, stream>>>(bufBp, we3, e3b, bufAp, HD);
    k_fc3<8,8,1><<<dim3(G8), blk, 0, stream>>>(bufAp, we4, e4b, d4p,  OCH);
    // horizontal GRU
    k_zrx<0><<<dim3(G8), blk, 0, stream>>>(hp, d4p, ctxp, wz1, wr1, wq1,
                                           z1b, r1b, q1b, bufAp, bufBp, qx);
    k_qh <0><<<dim3(G4), blk, 0, stream>>>(bufBp, wq1, qx, bufAp, hp);
    // vertical GRU
    k_zrx<1><<<dim3(G8), blk, 0, stream>>>(hp, d4p, ctxp, wz2, wr2, wq2,
                                           z2b, r2b, q2b, bufAp, bufBp, qx);
    k_qh <1><<<dim3(G4), blk, 0, stream>>>(bufBp, wq2, qx, bufAp, hp);
    // PHead
    k_fc3<8,4,1><<<dim3(G4), blk, 0, stream>>>(hp,    wp1, p1b, bufAp, HD);
    k_fc3<4,1,0><<<dim3(G1), blk, 0, stream>>>(bufAp, wp2, p2b, lgtsp, 16);
    k_stats<<<dim3(PXB), blk, 0, stream>>>(lgtsp, edges, cdp, out, it);
  }
}